// Round 8
// baseline (159.797 us; speedup 1.0000x reference)
//
#include <hip/hip_runtime.h>

typedef _Float16 half8 __attribute__((ext_vector_type(8)));
typedef _Float16 half4_t __attribute__((ext_vector_type(4)));
typedef float floatx4 __attribute__((ext_vector_type(4)));

// ---------------- prep kernel ----------------
// blocks [0, nb_gemm): per-node partial GEMM:
//   Ps[node][n] = sum_k x[node][k] * W1[n][1+k]    + b1[n]   (src half)
//   Pt[node][n] = sum_k x[node][k] * W1[n][65+k]             (tgt half)
//   Each block stages W1 cols 1..129 into LDS as MFMA A-frags (32 KB),
//   then each wave computes one 16-node tile (4 tiles/block).
// blocks [nb_gemm, nb_gemm+32): repack W2 -> MFMA A-frag order (w2f).
// block nb_gemm+32: pf = [b2(64) | W3(64)], c0h = fp16 W1[:,0].
__global__ __launch_bounds__(256) void prep_kernel(
    const float* __restrict__ x,
    const float* __restrict__ W1, const float* __restrict__ W2,
    const float* __restrict__ b1, const float* __restrict__ b2,
    const float* __restrict__ W3,
    _Float16* __restrict__ w2f, float* __restrict__ pf,
    _Float16* __restrict__ c0h,
    _Float16* __restrict__ Ps, _Float16* __restrict__ Pt,
    int n_nodes, int nb_gemm)
{
    const int b = blockIdx.x;
    const int tid = threadIdx.x;

    if (b < nb_gemm) {
        __shared__ __align__(16) _Float16 sW[16384];   // W1 A-frags, 32 KB
        // Stage W1 cols 1..129 -> LDS frag layout. SCALAR loads (W1 rows are
        // 129 floats -> float4 would be misaligned for 3/4 of rows; misaligned
        // dwordx4 is UB and a plausible cause of the round-7 container death).
        // frag pos for element (n,kk): (mt*4+kb)*512 + L*8 + jj with
        // mt=n>>4, kb=kk>>5, L=(n&15)|(((kk>>3)&3)<<4), jj=kk&7.
        for (int c = tid; c < 4096; c += 256) {
            int lin = c * 4;
            int n = lin >> 7, kk = lin & 127;
            const float* wp = W1 + n * 129 + 1 + kk;
            float w0 = wp[0], w1 = wp[1], w2 = wp[2], w3 = wp[3];
            int mt = n >> 4, kb = kk >> 5;
            int L = (n & 15) + (((kk >> 3) & 3) << 4);
            int pos = (mt * 4 + kb) * 512 + L * 8 + (kk & 7);
            half4_t h = {(_Float16)w0, (_Float16)w1, (_Float16)w2, (_Float16)w3};
            *(half4_t*)(&sW[pos]) = h;
        }
        __syncthreads();

        const int lane = tid & 63, wave = tid >> 6;
        const int lrow = lane & 15, quad = lane >> 4;
        const int tile = b * 4 + wave;
        if (tile * 16 < n_nodes) {
            int node = tile * 16 + lrow;
            if (node >= n_nodes) node = n_nodes - 1;
            // B-frags from x (fp32 -> fp16): lane (lrow,quad) elem j holds
            // x[node][quad*8+j] (bx0) / x[node][32+quad*8+j] (bx1).
            // x rows are 64 floats -> these float4 loads ARE 16B-aligned.
            const float* xr = x + (size_t)node * 64 + quad * 8;
            float4 x0 = *(const float4*)(xr);
            float4 x1 = *(const float4*)(xr + 4);
            float4 x2 = *(const float4*)(xr + 32);
            float4 x3 = *(const float4*)(xr + 36);
            half8 bx0 = {(_Float16)x0.x, (_Float16)x0.y, (_Float16)x0.z, (_Float16)x0.w,
                         (_Float16)x1.x, (_Float16)x1.y, (_Float16)x1.z, (_Float16)x1.w};
            half8 bx1 = {(_Float16)x2.x, (_Float16)x2.y, (_Float16)x2.z, (_Float16)x2.w,
                         (_Float16)x3.x, (_Float16)x3.y, (_Float16)x3.z, (_Float16)x3.w};
#pragma unroll
            for (int mt = 0; mt < 8; ++mt) {
                half8 a0 = *(const half8*)(&sW[(mt * 4 + 0) * 512 + lane * 8]);
                half8 a1 = *(const half8*)(&sW[(mt * 4 + 1) * 512 + lane * 8]);
                half8 a2 = *(const half8*)(&sW[(mt * 4 + 2) * 512 + lane * 8]);
                half8 a3 = *(const half8*)(&sW[(mt * 4 + 3) * 512 + lane * 8]);
                floatx4 ap = {0.f, 0.f, 0.f, 0.f};
                floatx4 at = {0.f, 0.f, 0.f, 0.f};
                ap = __builtin_amdgcn_mfma_f32_16x16x32_f16(a0, bx0, ap, 0, 0, 0);
                ap = __builtin_amdgcn_mfma_f32_16x16x32_f16(a1, bx1, ap, 0, 0, 0);
                at = __builtin_amdgcn_mfma_f32_16x16x32_f16(a2, bx0, at, 0, 0, 0);
                at = __builtin_amdgcn_mfma_f32_16x16x32_f16(a3, bx1, at, 0, 0, 0);
                int nb = mt * 16 + quad * 4;
                float4 b1v = *(const float4*)(b1 + nb);
                // D layout (m89): col = lane&15 (node), row = quad*4 + r (n).
                half4_t hs, ht;
                hs[0] = (_Float16)(ap[0] + b1v.x);
                hs[1] = (_Float16)(ap[1] + b1v.y);
                hs[2] = (_Float16)(ap[2] + b1v.z);
                hs[3] = (_Float16)(ap[3] + b1v.w);
                ht[0] = (_Float16)at[0];
                ht[1] = (_Float16)at[1];
                ht[2] = (_Float16)at[2];
                ht[3] = (_Float16)at[3];
                *(half4_t*)(Ps + (size_t)node * 128 + nb) = hs;
                *(half4_t*)(Pt + (size_t)node * 128 + nb) = ht;
            }
        }
    } else if (b < nb_gemm + 32) {
        int t = (b - nb_gemm) * 256 + tid;
        if (t < 8192) {                       // W2: 4 itiles x 4 kb x 512
            int c = t >> 9, r = t & 511;
            int L = r >> 3, jj = r & 7;
            int it = c >> 2, kb = c & 3;
            int i = it * 16 + (L & 15);
            int j = kb * 32 + (L >> 4) * 8 + jj;
            w2f[t] = (_Float16)W2[i * 128 + j];
        }
    } else {
        if (tid < 64)            pf[tid] = b2[tid];
        else if (tid < 128)      pf[tid] = W3[tid - 64];
        else                     c0h[tid - 128] = (_Float16)W1[(tid - 128) * 129];
    }
}

// ---------------- edge kernel ----------------
// No LDS, no barriers, no layer-1 MFMA. Each wave owns 32 edges (2 nt-tiles
// of 16). Per lane: build layer-2 B-frag directly:
//   bfr[kb][j] = relu(Ps[src][k] + Pt[tgt][k] + ew * c0[k]), k = kb*32+quad*8+j
// (packed fp16 VALU), then the proven layer-2/3 MFMA + shfl epilogue.
__global__ __launch_bounds__(256, 4) void edge_mlp_kernel(
    const _Float16* __restrict__ Ps, const _Float16* __restrict__ Pt,
    const int* __restrict__ ei, const float* __restrict__ ew,
    const float* __restrict__ b3,
    const _Float16* __restrict__ w2f, const float* __restrict__ pf,
    const _Float16* __restrict__ c0h,
    float* __restrict__ out, int E)
{
    const int tid  = threadIdx.x;
    const int lane = tid & 63;
    const int wave = tid >> 6;
    const int lrow = lane & 15;
    const int quad = lane >> 4;
    const int e0 = blockIdx.x * 128 + wave * 32;

    half8 c0f[4];
#pragma unroll
    for (int kb = 0; kb < 4; ++kb)
        c0f[kb] = *(const half8*)(c0h + kb * 32 + quad * 8);

    half8 bfr[2][4];
#pragma unroll
    for (int nt = 0; nt < 2; ++nt) {
        int e = e0 + nt * 16 + lrow; if (e >= E) e = E - 1;
        float ewf = ew[e];
        int sn = ei[e];
        int tn = ei[E + e];
        const _Float16* psp = Ps + (size_t)sn * 128 + quad * 8;
        const _Float16* ptp = Pt + (size_t)tn * 128 + quad * 8;
        _Float16 eh = (_Float16)ewf;
        half8 ev = {eh, eh, eh, eh, eh, eh, eh, eh};
        half8 z  = {0, 0, 0, 0, 0, 0, 0, 0};
#pragma unroll
        for (int kb = 0; kb < 4; ++kb) {
            half8 ps = *(const half8*)(psp + kb * 32);
            half8 pt = *(const half8*)(ptp + kb * 32);
            half8 s = ps + pt;          // b1 already folded into Ps
            s = s + ev * c0f[kb];       // fp-contract -> v_pk_fma_f16
            s = __builtin_elementwise_max(s, z);
            bfr[nt][kb] = s;
        }
    }

    const float b3v = b3[0];
    float tot0 = b3v, tot1 = b3v;
#pragma unroll
    for (int it = 0; it < 4; ++it) {
        half8 a2[4];
#pragma unroll
        for (int kb = 0; kb < 4; ++kb)
            a2[kb] = *(const half8*)(w2f + (it * 4 + kb) * 512 + lane * 8);
        int ib = it * 16 + quad * 4;
        float4 b2v = *(const float4*)(pf + ib);
        float4 w3v = *(const float4*)(pf + 64 + ib);
#pragma unroll
        for (int nt = 0; nt < 2; ++nt) {
            floatx4 a = {0.f, 0.f, 0.f, 0.f};
#pragma unroll
            for (int kb = 0; kb < 4; ++kb)
                a = __builtin_amdgcn_mfma_f32_16x16x32_f16(a2[kb], bfr[nt][kb], a, 0, 0, 0);
            float p = fmaxf(a[0] + b2v.x, 0.f) * w3v.x;
            p      += fmaxf(a[1] + b2v.y, 0.f) * w3v.y;
            p      += fmaxf(a[2] + b2v.z, 0.f) * w3v.z;
            p      += fmaxf(a[3] + b2v.w, 0.f) * w3v.w;
            p += __shfl_xor(p, 16, 64);
            p += __shfl_xor(p, 32, 64);
            if (nt == 0) tot0 += p; else tot1 += p;
        }
    }

    if (quad == 0) {
        int oe0 = e0 + lrow;
        int oe1 = e0 + 16 + lrow;
        if (oe0 < E) out[oe0] = tot0;
        if (oe1 < E) out[oe1] = tot1;
    }
}

extern "C" void kernel_launch(void* const* d_in, const int* in_sizes, int n_in,
                              void* d_out, int out_size, void* d_ws, size_t ws_size,
                              hipStream_t stream) {
    const float* x  = (const float*)d_in[0];
    const int*   ei = (const int*)d_in[1];   // int32 (verified round 1)
    const float* ew = (const float*)d_in[2];
    const float* W1 = (const float*)d_in[3];
    const float* b1 = (const float*)d_in[4];
    const float* W2 = (const float*)d_in[5];
    const float* b2 = (const float*)d_in[6];
    const float* W3 = (const float*)d_in[7];
    const float* b3 = (const float*)d_in[8];
    float* out = (float*)d_out;
    const int E = in_sizes[2];               // n_edges (800000)
    const int n_x = in_sizes[0];             // 3.2M floats
    const int n_nodes = n_x / 64;            // 50000

    // workspace layout:
    _Float16* w2f = (_Float16*)d_ws;                       // 16 KiB
    float*    pf  = (float*)((char*)d_ws + 16384);         // 512 B [b2|W3]
    _Float16* c0h = (_Float16*)((char*)d_ws + 16896);      // 256 B
    _Float16* Ps  = (_Float16*)((char*)d_ws + 17152);      // 12.8 MB
    _Float16* Pt  = (_Float16*)((char*)d_ws + 17152 + (size_t)n_nodes * 256);

    int tiles = (n_nodes + 15) / 16;
    int nb_gemm = (tiles + 3) / 4;
    prep_kernel<<<nb_gemm + 33, 256, 0, stream>>>(x, W1, W2, b1, b2, W3,
                                                  w2f, pf, c0h, Ps, Pt,
                                                  n_nodes, nb_gemm);

    int nblk = (E + 127) / 128;
    edge_mlp_kernel<<<nblk, 256, 0, stream>>>(Ps, Pt, ei, ew, b3,
                                              w2f, pf, c0h, out, E);
}

// Round 9
// 151.603 us; speedup vs baseline: 1.0540x; 1.0540x over previous
//
#include <hip/hip_runtime.h>

typedef _Float16 half8 __attribute__((ext_vector_type(8)));
typedef _Float16 half4_t __attribute__((ext_vector_type(4)));
typedef float floatx4 __attribute__((ext_vector_type(4)));

// ---------------- prep1: weight repack (cheap, round-0 proven) ----------------
// blocks [0,96): W1 cols 1..128 + W2 -> MFMA A-frag order in wsh (24576 halves).
// block 96: pf = [b2(64) | W3(64)], c0h = fp16 W1[:,0].
__global__ __launch_bounds__(256) void prep1_kernel(
    const float* __restrict__ W1, const float* __restrict__ W2,
    const float* __restrict__ b2, const float* __restrict__ W3,
    _Float16* __restrict__ wsh, float* __restrict__ pf, _Float16* __restrict__ c0h)
{
    int b = blockIdx.x;
    if (b < 96) {
        int tid = b * 256 + threadIdx.x;
        if (tid < 16384) {                    // W1 cols 1..128: 8 mtiles x 4 kb x 512
            int c = tid >> 9, r = tid & 511;
            int L = r >> 3, jj = r & 7;
            int mt = c >> 2, kb = c & 3;
            int n = mt * 16 + (L & 15);
            int k = kb * 32 + (L >> 4) * 8 + jj;
            wsh[tid] = (_Float16)W1[n * 129 + 1 + k];
        } else {                              // W2: 4 itiles x 4 kb x 512
            int t = tid - 16384;
            int c = t >> 9, r = t & 511;
            int L = r >> 3, jj = r & 7;
            int it = c >> 2, kb = c & 3;
            int i = it * 16 + (L & 15);
            int j = kb * 32 + (L >> 4) * 8 + jj;
            wsh[tid] = (_Float16)W2[i * 128 + j];
        }
    } else {
        int tid = threadIdx.x;
        if (tid < 64)        pf[tid] = b2[tid];
        else if (tid < 128)  pf[tid] = W3[tid - 64];
        else                 c0h[tid - 128] = (_Float16)W1[(tid - 128) * 129];
    }
}

// ---------------- prep2: per-node partial GEMM ----------------
//   Ps[node][n] = sum_k x[node][k] * W1[n][1+k]  + b1[n]   (src half)
//   Pt[node][n] = sum_k x[node][k] * W1[n][65+k]           (tgt half)
// Stages PRE-PACKED W1 frags from wsh into LDS with half8 copies (fast,
// vs round-8's 16K scalar loads/block), then 4 waves x 16-node tiles.
__global__ __launch_bounds__(256) void prep2_kernel(
    const float* __restrict__ x, const float* __restrict__ b1,
    const _Float16* __restrict__ wsh,
    _Float16* __restrict__ Ps, _Float16* __restrict__ Pt, int n_nodes)
{
    __shared__ __align__(16) _Float16 sW[16384];   // W1 A-frags, 32 KB
    const int tid = threadIdx.x;
    for (int c = tid; c < 2048; c += 256)
        *(half8*)(&sW[c * 8]) = *(const half8*)(wsh + c * 8);
    __syncthreads();

    const int lane = tid & 63, wave = tid >> 6;
    const int lrow = lane & 15, quad = lane >> 4;
    const int tile = blockIdx.x * 4 + wave;
    if (tile * 16 >= n_nodes) return;
    int node = tile * 16 + lrow;
    if (node >= n_nodes) node = n_nodes - 1;

    // B-frags from x (fp32 -> fp16); x rows are 64 floats, 16B-aligned.
    const float* xr = x + (size_t)node * 64 + quad * 8;
    float4 x0 = *(const float4*)(xr);
    float4 x1 = *(const float4*)(xr + 4);
    float4 x2 = *(const float4*)(xr + 32);
    float4 x3 = *(const float4*)(xr + 36);
    half8 bx0 = {(_Float16)x0.x, (_Float16)x0.y, (_Float16)x0.z, (_Float16)x0.w,
                 (_Float16)x1.x, (_Float16)x1.y, (_Float16)x1.z, (_Float16)x1.w};
    half8 bx1 = {(_Float16)x2.x, (_Float16)x2.y, (_Float16)x2.z, (_Float16)x2.w,
                 (_Float16)x3.x, (_Float16)x3.y, (_Float16)x3.z, (_Float16)x3.w};
#pragma unroll
    for (int mt = 0; mt < 8; ++mt) {
        half8 a0 = *(const half8*)(&sW[(mt * 4 + 0) * 512 + lane * 8]);
        half8 a1 = *(const half8*)(&sW[(mt * 4 + 1) * 512 + lane * 8]);
        half8 a2 = *(const half8*)(&sW[(mt * 4 + 2) * 512 + lane * 8]);
        half8 a3 = *(const half8*)(&sW[(mt * 4 + 3) * 512 + lane * 8]);
        floatx4 ap = {0.f, 0.f, 0.f, 0.f};
        floatx4 at = {0.f, 0.f, 0.f, 0.f};
        ap = __builtin_amdgcn_mfma_f32_16x16x32_f16(a0, bx0, ap, 0, 0, 0);
        ap = __builtin_amdgcn_mfma_f32_16x16x32_f16(a1, bx1, ap, 0, 0, 0);
        at = __builtin_amdgcn_mfma_f32_16x16x32_f16(a2, bx0, at, 0, 0, 0);
        at = __builtin_amdgcn_mfma_f32_16x16x32_f16(a3, bx1, at, 0, 0, 0);
        int nb = mt * 16 + quad * 4;
        float4 b1v = *(const float4*)(b1 + nb);
        // D layout (m89): col = lane&15 (node), row = quad*4 + r (n).
        half4_t hs, ht;
        hs[0] = (_Float16)(ap[0] + b1v.x);
        hs[1] = (_Float16)(ap[1] + b1v.y);
        hs[2] = (_Float16)(ap[2] + b1v.z);
        hs[3] = (_Float16)(ap[3] + b1v.w);
        ht[0] = (_Float16)at[0];
        ht[1] = (_Float16)at[1];
        ht[2] = (_Float16)at[2];
        ht[3] = (_Float16)at[3];
        *(half4_t*)(Ps + (size_t)node * 128 + nb) = hs;
        *(half4_t*)(Pt + (size_t)node * 128 + nb) = ht;
    }
}

// ---------------- edge kernel ----------------
// Per wave: 32 edges. Gathers Ps[src]/Pt[tgt] (irreducible 6.4M L2 lines),
// builds layer-2 B-frags with packed fp16 VALU, W2 frags staged ONCE per
// block into LDS via global_load_lds (kills the per-wave 16KB global
// re-reads that saturated the L2 request path). One barrier.
__global__ __launch_bounds__(256, 4) void edge_mlp_kernel(
    const _Float16* __restrict__ Ps, const _Float16* __restrict__ Pt,
    const int* __restrict__ ei, const float* __restrict__ ew,
    const float* __restrict__ b3,
    const _Float16* __restrict__ w2f, const float* __restrict__ pf,
    const _Float16* __restrict__ c0h,
    float* __restrict__ out, int E)
{
    __shared__ __align__(16) _Float16 sW2[8192];   // W2 A-frags, 16 KB

    const int tid  = threadIdx.x;
    const int lane = tid & 63;
    const int wave = tid >> 6;
    const int lrow = lane & 15;
    const int quad = lane >> 4;
    const int e0 = blockIdx.x * 128 + wave * 32;

    // ---- issue edge-index / edge-weight loads first ----
    int e_a = e0 + lrow;      if (e_a >= E) e_a = E - 1;
    int e_b = e0 + 16 + lrow; if (e_b >= E) e_b = E - 1;
    int sn0 = ei[e_a], tn0 = ei[E + e_a];
    int sn1 = ei[e_b], tn1 = ei[E + e_b];
    float ew0 = ew[e_a], ew1 = ew[e_b];

    // ---- stage W2 frags: wave-uniform LDS dest + lane*16B (linear) ----
#pragma unroll
    for (int i = 0; i < 4; ++i) {
        const _Float16* g = w2f + wave * 2048 + i * 512 + lane * 8;
        __builtin_amdgcn_global_load_lds(
            (const __attribute__((address_space(1))) void*)g,
            (__attribute__((address_space(3))) void*)&sW2[wave * 2048 + i * 512],
            16, 0, 0);
    }

    half8 c0f[4];
#pragma unroll
    for (int kb = 0; kb < 4; ++kb)
        c0f[kb] = *(const half8*)(c0h + kb * 32 + quad * 8);

    // ---- gather + combine: bfr[nt][kb] = relu(Ps[sn]+Pt[tn]+ew*c0) ----
    half8 bfr[2][4];
#pragma unroll
    for (int nt = 0; nt < 2; ++nt) {
        int sn = nt ? sn1 : sn0;
        int tn = nt ? tn1 : tn0;
        float ewf = nt ? ew1 : ew0;
        const _Float16* psp = Ps + (size_t)sn * 128 + quad * 8;
        const _Float16* ptp = Pt + (size_t)tn * 128 + quad * 8;
        _Float16 eh = (_Float16)ewf;
        half8 ev = {eh, eh, eh, eh, eh, eh, eh, eh};
        half8 z  = {0, 0, 0, 0, 0, 0, 0, 0};
#pragma unroll
        for (int kb = 0; kb < 4; ++kb) {
            half8 ps = *(const half8*)(psp + kb * 32);
            half8 pt = *(const half8*)(ptp + kb * 32);
            half8 s = ps + pt;          // b1 already folded into Ps
            s = s + ev * c0f[kb];
            s = __builtin_elementwise_max(s, z);
            bfr[nt][kb] = s;
        }
    }

    __syncthreads();   // drains vmcnt(0): sW2 staged, all waves may read

    // ---- layer 2 (+fused layer 3), A-frags from LDS ----
    const float b3v = b3[0];
    float tot0 = b3v, tot1 = b3v;
#pragma unroll
    for (int it = 0; it < 4; ++it) {
        half8 a2[4];
#pragma unroll
        for (int kb = 0; kb < 4; ++kb)
            a2[kb] = *(const half8*)(&sW2[(it * 4 + kb) * 512 + lane * 8]);
        int ib = it * 16 + quad * 4;
        float4 b2v = *(const float4*)(pf + ib);
        float4 w3v = *(const float4*)(pf + 64 + ib);
#pragma unroll
        for (int nt = 0; nt < 2; ++nt) {
            floatx4 a = {0.f, 0.f, 0.f, 0.f};
#pragma unroll
            for (int kb = 0; kb < 4; ++kb)
                a = __builtin_amdgcn_mfma_f32_16x16x32_f16(a2[kb], bfr[nt][kb], a, 0, 0, 0);
            float p = fmaxf(a[0] + b2v.x, 0.f) * w3v.x;
            p      += fmaxf(a[1] + b2v.y, 0.f) * w3v.y;
            p      += fmaxf(a[2] + b2v.z, 0.f) * w3v.z;
            p      += fmaxf(a[3] + b2v.w, 0.f) * w3v.w;
            p += __shfl_xor(p, 16, 64);
            p += __shfl_xor(p, 32, 64);
            if (nt == 0) tot0 += p; else tot1 += p;
        }
    }

    if (quad == 0) {
        int oe0 = e0 + lrow;
        int oe1 = e0 + 16 + lrow;
        if (oe0 < E) out[oe0] = tot0;
        if (oe1 < E) out[oe1] = tot1;
    }
}

extern "C" void kernel_launch(void* const* d_in, const int* in_sizes, int n_in,
                              void* d_out, int out_size, void* d_ws, size_t ws_size,
                              hipStream_t stream) {
    const float* x  = (const float*)d_in[0];
    const int*   ei = (const int*)d_in[1];   // int32 (verified round 1)
    const float* ew = (const float*)d_in[2];
    const float* W1 = (const float*)d_in[3];
    const float* b1 = (const float*)d_in[4];
    const float* W2 = (const float*)d_in[5];
    const float* b2 = (const float*)d_in[6];
    const float* W3 = (const float*)d_in[7];
    const float* b3 = (const float*)d_in[8];
    float* out = (float*)d_out;
    const int E = in_sizes[2];               // n_edges (800000)
    const int n_x = in_sizes[0];             // 3.2M floats
    const int n_nodes = n_x / 64;            // 50000

    // workspace layout:
    _Float16* wsh = (_Float16*)d_ws;                       // 49152 B (W1|W2 frags)
    float*    pf  = (float*)((char*)d_ws + 49152);         // 512 B [b2|W3]
    _Float16* c0h = (_Float16*)((char*)d_ws + 49664);      // 256 B
    _Float16* Ps  = (_Float16*)((char*)d_ws + 49920);      // 12.8 MB
    _Float16* Pt  = (_Float16*)((char*)d_ws + 49920 + (size_t)n_nodes * 256);

    prep1_kernel<<<97, 256, 0, stream>>>(W1, W2, b2, W3, wsh, pf, c0h);

    int tiles = (n_nodes + 15) / 16;
    int nb2 = (tiles + 3) / 4;
    prep2_kernel<<<nb2, 256, 0, stream>>>(x, b1, wsh, Ps, Pt, n_nodes);

    int nblk = (E + 127) / 128;
    edge_mlp_kernel<<<nblk, 256, 0, stream>>>(Ps, Pt, ei, ew, b3,
                                              wsh + 16384, pf, c0h, out, E);
}